// Round 18
// baseline (95.794 us; speedup 1.0000x reference)
//
#include <hip/hip_runtime.h>

// CRF loss: A=8, S=200, B=64, T=32. scores (A,S,B,T,T) f32, targets (A,S,B) i32,
// mask (S,B) bool, a_mask (A,B) bool -- bool width (u8 vs i32) runtime-detected.
// Base = R12 (CHAMPION 80.5us), verbatim except the consumer loop:
// e-reads are software-pipelined ONE step ahead into NAMED scalar registers
// (e0_..e15_ <- n0_..n15_ value moves; the proven R6/R7 register-rotation
// idiom -- no arrays, no conditional liveness -> no scratch demotion, no
// unroll). w-reads issue BEFORE the n-loads so the compiler's counted
// lgkmcnt wait covers only w, hiding e-latency under the fma/shfl chain.
constexpr int A_ = 8, S_ = 200, B_ = 64, T_ = 32;
constexpr int START_TAG = 30, END_TAG = 31;
constexpr int NW = 8;                      // waves per block = tiles per phase
#define LOG2E 1.44269504088896340736f
#define LN2   0.69314718055994530942f

#if __has_builtin(__builtin_amdgcn_exp2f)
#define EXP2F(x) __builtin_amdgcn_exp2f(x)
#else
#define EXP2F(x) __expf((x) * LN2)
#endif

__device__ __forceinline__ int load_flag(const void* p, bool u8, int idx) {
    return u8 ? (int)((const unsigned char*)p)[idx] : ((const int*)p)[idx];
}

// LDS-writes-visible barrier WITHOUT vmcnt drain (proven R7/R12).
#define LGKM_BARRIER do {                                                \
        asm volatile("s_waitcnt lgkmcnt(0)" ::: "memory");               \
        __builtin_amdgcn_s_barrier();                                    \
        asm volatile("" ::: "memory");                                   \
    } while (0)

__global__ __launch_bounds__(NW * 64, 4)   // pin VGPR <= 128: keep 2 blocks/CU
void crf_loss_kernel(const float* __restrict__ scores,
                     const int* __restrict__ targets,
                     const void* __restrict__ mask,
                     const void* __restrict__ amask,
                     float* __restrict__ out)
{
    const int chain = blockIdx.x;          // 0..511
    const int a = chain >> 6;
    const int b = chain & (B_ - 1);
    const int tid = threadIdx.x;
    const int wv = tid >> 6;               // wave 0..7 (wave 0 also consumes)
    const int lane = tid & 63;
    const int t = lane & 31;
    const int fbase = (lane >> 5) << 4;    // 0 or 16

    // bool width detect: mask row 0 is all-true. int view: 1 -> int32, 0x01010101 -> uint8
    const bool bool_u8 = (((const int*)mask)[0] != 1);
    if (!load_flag(amask, bool_u8, a * B_ + b)) return;   // uniform block exit

    __shared__ __align__(16) float ebuf[2][NW][T_ * T_];  // 2 x 8 x 4KB exp-tiles
    __shared__ float gside[2][NW];                        // raw gold-path scores
    __shared__ int tg_lds[S_];
    __shared__ float wlds[T_];                            // w vector (wave 0 only)

    // ---- first false mask index L (prefix mask) ----
    int L = S_;
    for (int base = 0; base < S_; base += 64) {
        int i = base + lane;
        int mv = (i < S_) ? load_flag(mask, bool_u8, i * B_ + b) : 1;
        unsigned long long bal = __ballot(mv == 0);
        if (bal != 0ull && L == S_) L = base + (int)__builtin_ctzll(bal);
    }

    for (int i = tid; i < S_; i += NW * 64)
        tg_lds[i] = targets[((size_t)a * S_ + i) * B_ + b];
    __syncthreads();                        // tg_lds ready (drain fine in prologue)

    const size_t s_stride = (size_t)B_ * T_ * T_;         // 65536 floats per step
    const float* cb = scores + ((size_t)a * S_ * B_ + b) * (T_ * T_);

    float wcur = 0.0f, C2 = 0.0f, tg = 0.0f;
    if (wv == 0) {                          // consumer init
        wcur = EXP2F(cb[START_TAG * T_ + t] * LOG2E);
        if (lane < 32) wlds[lane] = wcur;
        tg = cb[tg_lds[0]];
    }

    const int nch = (L - 1 + NW - 1) / NW;  // phases (block-uniform)

#define E4(DST, SRC) do {                                                \
        DST.x = EXP2F(SRC.x * LOG2E); DST.y = EXP2F(SRC.y * LOG2E);      \
        DST.z = EXP2F(SRC.z * LOG2E); DST.w = EXP2F(SRC.w * LOG2E);      \
    } while (0)

#define RENORM do {                                                      \
        float m_ = wcur;                                                 \
        m_ = fmaxf(m_, __shfl_xor(m_, 1));                               \
        m_ = fmaxf(m_, __shfl_xor(m_, 2));                               \
        m_ = fmaxf(m_, __shfl_xor(m_, 4));                               \
        m_ = fmaxf(m_, __shfl_xor(m_, 8));                               \
        m_ = fmaxf(m_, __shfl_xor(m_, 16));                              \
        int eb_ = (__float_as_int(m_) >> 23) & 0xff;                     \
        C2 += (float)(eb_ - 127);                                        \
        float sc2_ = __int_as_float((254 - eb_) << 23);                  \
        wcur *= sc2_;                                                    \
        if (lane < 32) wlds[lane] = wcur;                                \
    } while (0)

#define TLOAD(Q0, Q1, Q2, Q3, GR, SC) do {                               \
        const int s_ = (SC);                                             \
        if (s_ < L) {                                                    \
            const float*  p_  = cb + (size_t)s_ * s_stride;              \
            const float4* p4_ = (const float4*)p_;                       \
            Q0 = p4_[lane];       Q1 = p4_[64 + lane];                   \
            Q2 = p4_[128 + lane]; Q3 = p4_[192 + lane];                  \
            GR = p_[tg_lds[s_]];                                         \
        }                                                                \
    } while (0)

#define ELOAD16(P0,P1,P2,P3,P4,P5,P6,P7,P8,P9,P10,P11,P12,P13,P14,P15, EBP) do { \
        const float* eb_ = (EBP);                                        \
        P0  = eb_[((fbase +  0) << 5) | t];                              \
        P1  = eb_[((fbase +  1) << 5) | t];                              \
        P2  = eb_[((fbase +  2) << 5) | t];                              \
        P3  = eb_[((fbase +  3) << 5) | t];                              \
        P4  = eb_[((fbase +  4) << 5) | t];                              \
        P5  = eb_[((fbase +  5) << 5) | t];                              \
        P6  = eb_[((fbase +  6) << 5) | t];                              \
        P7  = eb_[((fbase +  7) << 5) | t];                              \
        P8  = eb_[((fbase +  8) << 5) | t];                              \
        P9  = eb_[((fbase +  9) << 5) | t];                              \
        P10 = eb_[((fbase + 10) << 5) | t];                              \
        P11 = eb_[((fbase + 11) << 5) | t];                              \
        P12 = eb_[((fbase + 12) << 5) | t];                              \
        P13 = eb_[((fbase + 13) << 5) | t];                              \
        P14 = eb_[((fbase + 14) << 5) | t];                              \
        P15 = eb_[((fbase + 15) << 5) | t];                              \
    } while (0)

    // consumer phase: runtime j-loop with 1-step e-prefetch in NAMED registers.
    // Source order inside the loop: w-reads first, then next-e loads, then the
    // w-dependent math -- compiler's counted lgkmcnt waits on w only.
#define CONSUME(KK) do {                                                 \
        const int kb_ = (KK) & 1;                                        \
        const int jmax_ = min(NW, L - 1 - (KK) * NW);                    \
        float e0_,e1_,e2_,e3_,e4_,e5_,e6_,e7_,                           \
              e8_,e9_,e10_,e11_,e12_,e13_,e14_,e15_;                     \
        ELOAD16(e0_,e1_,e2_,e3_,e4_,e5_,e6_,e7_,                         \
                e8_,e9_,e10_,e11_,e12_,e13_,e14_,e15_, &ebuf[kb_][0][0]);\
        for (int j = 0; j < jmax_; ++j) {                                \
            float4 wa_ = *(const float4*)&wlds[fbase];                   \
            float4 wb_ = *(const float4*)&wlds[fbase + 4];               \
            float4 wc_ = *(const float4*)&wlds[fbase + 8];               \
            float4 wd_ = *(const float4*)&wlds[fbase + 12];              \
            const int jn_ = (j + 1 < jmax_) ? j + 1 : j;                 \
            float n0_,n1_,n2_,n3_,n4_,n5_,n6_,n7_,                       \
                  n8_,n9_,n10_,n11_,n12_,n13_,n14_,n15_;                 \
            ELOAD16(n0_,n1_,n2_,n3_,n4_,n5_,n6_,n7_,                     \
                    n8_,n9_,n10_,n11_,n12_,n13_,n14_,n15_,               \
                    &ebuf[kb_][jn_][0]);                                 \
            float s0_ = fmaf(e3_, wa_.w, fmaf(e2_, wa_.z,                \
                        fmaf(e1_, wa_.y, e0_ * wa_.x)));                 \
            float s1_ = fmaf(e7_, wb_.w, fmaf(e6_, wb_.z,                \
                        fmaf(e5_, wb_.y, e4_ * wb_.x)));                 \
            float s2_ = fmaf(e11_, wc_.w, fmaf(e10_, wc_.z,              \
                        fmaf(e9_, wc_.y, e8_ * wc_.x)));                 \
            float s3_ = fmaf(e15_, wd_.w, fmaf(e14_, wd_.z,              \
                        fmaf(e13_, wd_.y, e12_ * wd_.x)));               \
            float s_ = (s0_ + s1_) + (s2_ + s3_);                        \
            s_ += __shfl_xor(s_, 32);                                    \
            wcur = s_;                                                   \
            if (lane < 32) wlds[lane] = s_;                              \
            tg += gside[kb_][j];                                         \
            const int sidx_ = 1 + (KK) * NW + j;                         \
            if ((sidx_ & 3) == 0) RENORM;                                \
            e0_ = n0_;  e1_ = n1_;  e2_ = n2_;  e3_ = n3_;               \
            e4_ = n4_;  e5_ = n5_;  e6_ = n6_;  e7_ = n7_;               \
            e8_ = n8_;  e9_ = n9_;  e10_ = n10_; e11_ = n11_;            \
            e12_ = n12_; e13_ = n13_; e14_ = n14_; e15_ = n15_;          \
        }                                                                \
    } while (0)

    // One phase with buffer set (Q0..Q3,GQ): exp-write chunk KK, refill the
    // SAME regs with chunk KK+2 (first read 2 phases later), raw barrier,
    // wave-0 consume. No register rotation (proven R12).
#define PHASE(Q0, Q1, Q2, Q3, GQ, KK) do {                               \
        const int k_ = (KK);                                             \
        const int scur_ = 1 + k_ * NW + wv;                              \
        if (scur_ < L) {                                                 \
            float4* ebw = (float4*)&ebuf[k_ & 1][wv][0];                 \
            float4 e0, e1, e2, e3;                                       \
            E4(e0, Q0); E4(e1, Q1); E4(e2, Q2); E4(e3, Q3);              \
            ebw[lane] = e0; ebw[64 + lane] = e1;                         \
            ebw[128 + lane] = e2; ebw[192 + lane] = e3;                  \
            if (lane == 0) gside[k_ & 1][wv] = GQ;                       \
        }                                                                \
        TLOAD(Q0, Q1, Q2, Q3, GQ, scur_ + 2 * NW);                       \
        LGKM_BARRIER;                                                    \
        if (wv == 0) CONSUME(k_);                                        \
    } while (0)

    // ---- prologue prefetch: chunk 0 -> A, chunk 1 -> B ----
    float4 a0, a1, a2, a3, b0, b1, b2, b3;
    float ga = 0.0f, gb = 0.0f;
    TLOAD(a0, a1, a2, a3, ga, 1 + wv);
    TLOAD(b0, b1, b2, b3, gb, 1 + NW + wv);

    for (int k = 0; k < nch; k += 2) {
        PHASE(a0, a1, a2, a3, ga, k);
        if (k + 1 < nch)
            PHASE(b0, b1, b2, b3, gb, k + 1);
    }

    // ---- epilogue (consumer): logZ = ln(w[END_TAG]) + C2*ln2 ----
    if (wv == 0) {
        float wend = __shfl(wcur, END_TAG);
        float logZ = __logf(wend) + C2 * LN2;
        if (lane == 0)
            atomicAdd(out, (logZ - tg) * (1.0f / (float)B_));
    }
}

extern "C" void kernel_launch(void* const* d_in, const int* in_sizes, int n_in,
                              void* d_out, int out_size, void* d_ws, size_t ws_size,
                              hipStream_t stream) {
    const float* scores = (const float*)d_in[0];
    const int* targets  = (const int*)d_in[1];
    const void* mask    = d_in[2];
    const void* amask   = d_in[3];
    float* out = (float*)d_out;

    hipMemsetAsync(out, 0, sizeof(float), stream);
    crf_loss_kernel<<<dim3(A_ * B_), dim3(NW * 64), 0, stream>>>(
        scores, targets, mask, amask, out);
}

// Round 19
// 89.486 us; speedup vs baseline: 1.0705x; 1.0705x over previous
//
#include <hip/hip_runtime.h>
#include <stdint.h>

// CRF loss: A=8, S=200, B=64, T=32. scores (A,S,B,T,T) f32, targets (A,S,B) i32,
// mask (S,B) bool, a_mask (A,B) bool -- bool width (u8 vs i32) runtime-detected.
// R19: PAIR-PRODUCT pipeline. 8 producer waves + 1 dedicated consumer wave.
// Per phase (16 original steps): producer wave w loads tiles s1=1+k*16+2w and
// s2=s1+1, computes P = M_s1 * M_s2 via MFMA 32x32x16 bf16 (R14-verified
// C/D-init + MULT, absmax 0.0), scatters P (f32) to ebuf[f*32+t]; consumer
// folds 8 PAIR-steps per phase (halves the serial chain: 199 -> 100 steps).
// Sync skeleton = R12 champion: raw lgkm-only barrier, runtime consumer
// j-loop (unroll is miscompile-cursed), use-then-reload prefetch registers
// (cover = full consume phase), renorm every 2 pair-steps (pow2-exact).
constexpr int A_ = 8, S_ = 200, B_ = 64, T_ = 32;
constexpr int START_TAG = 30, END_TAG = 31;
constexpr int NW = 8;                      // producer waves
constexpr int NT = (NW + 1) * 64;          // 576 threads; wave 8 = consumer
constexpr int JPH = 16;                    // original steps per phase
#define LOG2E 1.44269504088896340736f
#define LN2   0.69314718055994530942f

#if __has_builtin(__builtin_amdgcn_exp2f)
#define EXP2F(x) __builtin_amdgcn_exp2f(x)
#else
#define EXP2F(x) __expf((x) * LN2)
#endif

typedef short short8 __attribute__((ext_vector_type(8)));
typedef float float16 __attribute__((ext_vector_type(16)));

__device__ __forceinline__ int load_flag(const void* p, bool u8, int idx) {
    return u8 ? (int)((const unsigned char*)p)[idx] : ((const int*)p)[idx];
}

// f32 -> bf16 bits, round-to-nearest-even (inputs are positive finite).
__device__ __forceinline__ short f2bf(float x) {
    uint32_t u = __float_as_uint(x);
    u += 0x7fffu + ((u >> 16) & 1u);
    return (short)(u >> 16);
}

// LDS-writes-visible barrier WITHOUT vmcnt drain (proven R7/R12).
#define LGKM_BARRIER do {                                                \
        asm volatile("s_waitcnt lgkmcnt(0)" ::: "memory");               \
        __builtin_amdgcn_s_barrier();                                    \
        asm volatile("" ::: "memory");                                   \
    } while (0)

__global__ __launch_bounds__(NT)
void crf_loss_kernel(const float* __restrict__ scores,
                     const int* __restrict__ targets,
                     const void* __restrict__ mask,
                     const void* __restrict__ amask,
                     float* __restrict__ out)
{
    const int chain = blockIdx.x;          // 0..511
    const int a = chain >> 6;
    const int b = chain & (B_ - 1);
    const int tid = threadIdx.x;
    const int wv = tid >> 6;               // 0..7 producers, 8 consumer
    const int lane = tid & 63;
    const int t = lane & 31;
    const int fbase = (lane >> 5) << 4;    // 0 or 16 (consumer)
    const int col = lane & 31;             // MFMA col (producer)
    const int h = lane >> 5;               // MFMA half (producer)

    // bool width detect: mask row 0 is all-true. int view: 1 -> int32, 0x01010101 -> uint8
    const bool bool_u8 = (((const int*)mask)[0] != 1);
    if (!load_flag(amask, bool_u8, a * B_ + b)) return;   // uniform block exit

    __shared__ __align__(16) float ebuf[2][NW][T_ * T_];  // pair products, f32 [f*32+t]
    __shared__ float gside[2][NW];                        // pair gold-score sums
    __shared__ int tg_lds[S_];
    __shared__ float wlds[T_];                            // w vector (consumer)

    // ---- first false mask index L (prefix mask) ----
    int L = S_;
    for (int base = 0; base < S_; base += 64) {
        int i = base + lane;
        int mv = (i < S_) ? load_flag(mask, bool_u8, i * B_ + b) : 1;
        unsigned long long bal = __ballot(mv == 0);
        if (bal != 0ull && L == S_) L = base + (int)__builtin_ctzll(bal);
    }

    for (int i = tid; i < S_; i += NT)
        tg_lds[i] = targets[((size_t)a * S_ + i) * B_ + b];
    __syncthreads();                        // tg_lds ready

    const size_t s_stride = (size_t)B_ * T_ * T_;         // 65536 floats per step
    const float* cb = scores + ((size_t)a * S_ * B_ + b) * (T_ * T_);

    float wcur = 0.0f, C2 = 0.0f, tg = 0.0f;
    if (wv == NW) {                         // consumer init
        wcur = EXP2F(cb[START_TAG * T_ + t] * LOG2E);
        if (lane < 32) wlds[lane] = wcur;
        tg = cb[tg_lds[0]];
    }

    const int nch = (L - 1 + JPH - 1) / JPH;   // phases (block-uniform)

#define RENORM do {                                                      \
        float m_ = wcur;                                                 \
        m_ = fmaxf(m_, __shfl_xor(m_, 1));                               \
        m_ = fmaxf(m_, __shfl_xor(m_, 2));                               \
        m_ = fmaxf(m_, __shfl_xor(m_, 4));                               \
        m_ = fmaxf(m_, __shfl_xor(m_, 8));                               \
        m_ = fmaxf(m_, __shfl_xor(m_, 16));                              \
        int eb_ = (__float_as_int(m_) >> 23) & 0xff;                     \
        C2 += (float)(eb_ - 127);                                        \
        float sc2_ = __int_as_float((254 - eb_) << 23);                  \
        wcur *= sc2_;                                                    \
        if (lane < 32) wlds[lane] = wcur;                                \
    } while (0)

    // ---- producer prefetch registers (one set; cover = rest of phase + consume) ----
    float4 Xa, Xb, Xc, Xd;                  // A-tile (M_s1), raw, A-fragment rows
    float16 ci;                             // C-init tile (M_s2 or M_s1), raw, C/D layout
    float gp = 0.0f;                        // pair gold-score sum (uniform)
    int act = 0, domult = 0;

    // Load pair (s1,s2) of chunk KK into the prefetch registers.
#define TLOADP(KK) do {                                                  \
        const int s1_ = 1 + (KK) * JPH + 2 * wv;                         \
        const int s2_ = s1_ + 1;                                         \
        act = (s1_ < L);                                                 \
        domult = (s2_ < L);                                              \
        if (act) {                                                       \
            const float* p1_ = cb + (size_t)s1_ * s_stride;              \
            const float* ap_ = p1_ + col * T_ + h * 8;                   \
            Xa = *(const float4*)(ap_);                                  \
            Xb = *(const float4*)(ap_ + 4);                              \
            Xc = *(const float4*)(ap_ + 16);                             \
            Xd = *(const float4*)(ap_ + 20);                             \
            const float* p2_ = cb + (size_t)(domult ? s2_ : s1_) * s_stride; \
            _Pragma("unroll")                                            \
            for (int reg = 0; reg < 16; ++reg) {                         \
                int row_ = (reg & 3) + 8 * (reg >> 2) + 4 * h;           \
                ci[reg] = p2_[row_ * T_ + col];                          \
            }                                                            \
            float g1_ = p1_[tg_lds[s1_]];                                \
            float g2_ = domult ? p2_[tg_lds[s2_]] : 0.0f;                \
            gp = g1_ + g2_;                                              \
        }                                                                \
    } while (0)

    // Produce pair product into ebuf half (KK&1): c = exp(ci); if domult,
    // c = exp(X-tile) * c via MFMA (R14-verified MULT); scatter f32.
#define PRODUCE(KK) do {                                                 \
        if (act) {                                                       \
            float16 c;                                                   \
            _Pragma("unroll")                                            \
            for (int reg = 0; reg < 16; ++reg)                           \
                c[reg] = EXP2F(ci[reg] * LOG2E);                         \
            if (domult) {                                                \
                const float16 zf = {0,0,0,0, 0,0,0,0, 0,0,0,0, 0,0,0,0}; \
                short8 a1, a2;                                           \
                a1[0] = f2bf(EXP2F(Xa.x * LOG2E)); a1[1] = f2bf(EXP2F(Xa.y * LOG2E)); \
                a1[2] = f2bf(EXP2F(Xa.z * LOG2E)); a1[3] = f2bf(EXP2F(Xa.w * LOG2E)); \
                a1[4] = f2bf(EXP2F(Xb.x * LOG2E)); a1[5] = f2bf(EXP2F(Xb.y * LOG2E)); \
                a1[6] = f2bf(EXP2F(Xb.z * LOG2E)); a1[7] = f2bf(EXP2F(Xb.w * LOG2E)); \
                a2[0] = f2bf(EXP2F(Xc.x * LOG2E)); a2[1] = f2bf(EXP2F(Xc.y * LOG2E)); \
                a2[2] = f2bf(EXP2F(Xc.z * LOG2E)); a2[3] = f2bf(EXP2F(Xc.w * LOG2E)); \
                a2[4] = f2bf(EXP2F(Xd.x * LOG2E)); a2[5] = f2bf(EXP2F(Xd.y * LOG2E)); \
                a2[6] = f2bf(EXP2F(Xd.z * LOG2E)); a2[7] = f2bf(EXP2F(Xd.w * LOG2E)); \
                uint32_t pk[8], sw[8];                                   \
                _Pragma("unroll")                                        \
                for (int p = 0; p < 8; ++p) {                            \
                    pk[p] = ((uint32_t)(uint16_t)f2bf(c[2 * p + 1]) << 16) \
                          |  (uint32_t)(uint16_t)f2bf(c[2 * p]);         \
                    sw[p] = (uint32_t)__shfl_xor((int)pk[p], 32);        \
                }                                                        \
                union { uint32_t d[4]; short8 v; } b1u, b2u;             \
                b1u.d[0] = h ? sw[2] : pk[0];                            \
                b1u.d[1] = h ? sw[3] : pk[1];                            \
                b1u.d[2] = h ? pk[2] : sw[0];                            \
                b1u.d[3] = h ? pk[3] : sw[1];                            \
                b2u.d[0] = h ? sw[6] : pk[4];                            \
                b2u.d[1] = h ? sw[7] : pk[5];                            \
                b2u.d[2] = h ? pk[6] : sw[4];                            \
                b2u.d[3] = h ? pk[7] : sw[5];                            \
                float16 d_ = __builtin_amdgcn_mfma_f32_32x32x16_bf16(a1, b1u.v, zf, 0, 0, 0); \
                d_ = __builtin_amdgcn_mfma_f32_32x32x16_bf16(a2, b2u.v, d_, 0, 0, 0); \
                c = d_;                                                  \
            }                                                            \
            float* ebw = &ebuf[(KK) & 1][wv][0];                         \
            _Pragma("unroll")                                            \
            for (int reg = 0; reg < 16; ++reg) {                         \
                int row_ = (reg & 3) + 8 * (reg >> 2) + 4 * h;           \
                ebw[(row_ << 5) | col] = c[reg];                         \
            }                                                            \
            if (lane == 0) gside[(KK) & 1][wv] = gp;                     \
        }                                                                \
    } while (0)

    // consumer phase: runtime j-loop over PAIR matrices (verbatim R12 form)
#define CONSUME(KK) do {                                                 \
        const int kb_ = (KK) & 1;                                        \
        const int rem_ = L - 1 - (KK) * JPH;                             \
        const int steps_ = (rem_ < JPH) ? rem_ : JPH;                    \
        const int pairs_ = (steps_ + 1) >> 1;                            \
        for (int j = 0; j < pairs_; ++j) {                               \
            const float* eb = &ebuf[kb_][j][0];                          \
            float4 wa_ = *(const float4*)&wlds[fbase];                   \
            float4 wb_ = *(const float4*)&wlds[fbase + 4];               \
            float4 wc_ = *(const float4*)&wlds[fbase + 8];               \
            float4 wd_ = *(const float4*)&wlds[fbase + 12];              \
            float e_[16];                                                \
            _Pragma("unroll")                                            \
            for (int i = 0; i < 16; ++i)                                 \
                e_[i] = eb[((fbase + i) << 5) | t];                      \
            float s0_ = fmaf(e_[3], wa_.w, fmaf(e_[2], wa_.z,            \
                        fmaf(e_[1], wa_.y, e_[0] * wa_.x)));             \
            float s1_ = fmaf(e_[7], wb_.w, fmaf(e_[6], wb_.z,            \
                        fmaf(e_[5], wb_.y, e_[4] * wb_.x)));             \
            float s2_ = fmaf(e_[11], wc_.w, fmaf(e_[10], wc_.z,          \
                        fmaf(e_[9], wc_.y, e_[8] * wc_.x)));             \
            float s3_ = fmaf(e_[15], wd_.w, fmaf(e_[14], wd_.z,          \
                        fmaf(e_[13], wd_.y, e_[12] * wd_.x)));           \
            float s_ = (s0_ + s1_) + (s2_ + s3_);                        \
            s_ += __shfl_xor(s_, 32);                                    \
            wcur = s_;                                                   \
            if (lane < 32) wlds[lane] = s_;                              \
            tg += gside[kb_][j];                                         \
            if (j & 1) RENORM;                                           \
        }                                                                \
    } while (0)

    // ---- prologue prefetch: chunk 0 pair ----
    if (wv < NW) TLOADP(0);

    for (int k = 0; k < nch; ++k) {
        if (wv < NW) {
            PRODUCE(k);                     // uses prefetched regs (chunk k)
            TLOADP(k + 1);                  // refill; cover = barrier + consume
        }
        LGKM_BARRIER;                       // ebuf half (k&1) published
        if (wv == NW) CONSUME(k);
    }

    // ---- epilogue (consumer): logZ = ln(w[END_TAG]) + C2*ln2 ----
    if (wv == NW) {
        float wend = __shfl(wcur, END_TAG);
        float logZ = __logf(wend) + C2 * LN2;
        if (lane == 0)
            atomicAdd(out, (logZ - tg) * (1.0f / (float)B_));
    }
}

extern "C" void kernel_launch(void* const* d_in, const int* in_sizes, int n_in,
                              void* d_out, int out_size, void* d_ws, size_t ws_size,
                              hipStream_t stream) {
    const float* scores = (const float*)d_in[0];
    const int* targets  = (const int*)d_in[1];
    const void* mask    = d_in[2];
    const void* amask   = d_in[3];
    float* out = (float*)d_out;

    hipMemsetAsync(out, 0, sizeof(float), stream);
    crf_loss_kernel<<<dim3(A_ * B_), dim3(NT), 0, stream>>>(
        scores, targets, mask, amask, out);
}

// Round 20
// 72.972 us; speedup vs baseline: 1.3128x; 1.2263x over previous
//
#include <hip/hip_runtime.h>

// CRF loss: A=8, S=200, B=64, T=32. scores (A,S,B,T,T) f32, targets (A,S,B) i32,
// mask (S,B) bool, a_mask (A,B) bool -- bool width (u8 vs i32) runtime-detected.
// Base = R12 (CHAMPION 80.5us) with SUBTRACT-ONLY consumer edits:
//  (1) gold-path tg accumulated by PRODUCERS (tgacc += GQ at exp-write, guarded
//      by scur_<L), handed off via LDS once after the loop -- consumer loses a
//      gside read + add per step; gside deleted.
//  (2) renorm once per phase (every 8 steps), hoisted after the j-loop -- no
//      per-step s/branch. Safe: growth <= 2^104/phase, w-spread <= 2^16 always.
// Everything else verbatim R12: 8-wave block, wave 0 producer+consumer, named
// A/B register sets (2-phase cover), raw lgkm-only barrier, runtime j-loop.
constexpr int A_ = 8, S_ = 200, B_ = 64, T_ = 32;
constexpr int START_TAG = 30, END_TAG = 31;
constexpr int NW = 8;                      // waves per block = tiles per phase
#define LOG2E 1.44269504088896340736f
#define LN2   0.69314718055994530942f

#if __has_builtin(__builtin_amdgcn_exp2f)
#define EXP2F(x) __builtin_amdgcn_exp2f(x)
#else
#define EXP2F(x) __expf((x) * LN2)
#endif

__device__ __forceinline__ int load_flag(const void* p, bool u8, int idx) {
    return u8 ? (int)((const unsigned char*)p)[idx] : ((const int*)p)[idx];
}

// LDS-writes-visible barrier WITHOUT vmcnt drain (proven R7/R12).
#define LGKM_BARRIER do {                                                \
        asm volatile("s_waitcnt lgkmcnt(0)" ::: "memory");               \
        __builtin_amdgcn_s_barrier();                                    \
        asm volatile("" ::: "memory");                                   \
    } while (0)

__global__ __launch_bounds__(NW * 64)
void crf_loss_kernel(const float* __restrict__ scores,
                     const int* __restrict__ targets,
                     const void* __restrict__ mask,
                     const void* __restrict__ amask,
                     float* __restrict__ out)
{
    const int chain = blockIdx.x;          // 0..511
    const int a = chain >> 6;
    const int b = chain & (B_ - 1);
    const int tid = threadIdx.x;
    const int wv = tid >> 6;               // wave 0..7 (wave 0 also consumes)
    const int lane = tid & 63;
    const int t = lane & 31;
    const int fbase = (lane >> 5) << 4;    // 0 or 16

    // bool width detect: mask row 0 is all-true. int view: 1 -> int32, 0x01010101 -> uint8
    const bool bool_u8 = (((const int*)mask)[0] != 1);
    if (!load_flag(amask, bool_u8, a * B_ + b)) return;   // uniform block exit

    __shared__ __align__(16) float ebuf[2][NW][T_ * T_];  // 2 x 8 x 4KB exp-tiles
    __shared__ int tg_lds[S_];
    __shared__ float wlds[T_];                            // w vector (wave 0 only)
    __shared__ float gfin[NW];                            // per-wave gold sums

    // ---- first false mask index L (prefix mask) ----
    int L = S_;
    for (int base = 0; base < S_; base += 64) {
        int i = base + lane;
        int mv = (i < S_) ? load_flag(mask, bool_u8, i * B_ + b) : 1;
        unsigned long long bal = __ballot(mv == 0);
        if (bal != 0ull && L == S_) L = base + (int)__builtin_ctzll(bal);
    }

    for (int i = tid; i < S_; i += NW * 64)
        tg_lds[i] = targets[((size_t)a * S_ + i) * B_ + b];
    __syncthreads();                        // tg_lds ready (drain fine in prologue)

    const size_t s_stride = (size_t)B_ * T_ * T_;         // 65536 floats per step
    const float* cb = scores + ((size_t)a * S_ * B_ + b) * (T_ * T_);

    float wcur = 0.0f, C2 = 0.0f, tg0 = 0.0f;
    if (wv == 0) {                          // consumer init
        wcur = EXP2F(cb[START_TAG * T_ + t] * LOG2E);
        if (lane < 32) wlds[lane] = wcur;
        tg0 = cb[tg_lds[0]];                // gold score, step 0
    }
    float tgacc = 0.0f;                     // per-wave gold accumulation (uniform)

    const int nch = (L - 1 + NW - 1) / NW;  // phases (block-uniform)

#define E4(DST, SRC) do {                                                \
        DST.x = EXP2F(SRC.x * LOG2E); DST.y = EXP2F(SRC.y * LOG2E);      \
        DST.z = EXP2F(SRC.z * LOG2E); DST.w = EXP2F(SRC.w * LOG2E);      \
    } while (0)

#define RENORM do {                                                      \
        float m_ = wcur;                                                 \
        m_ = fmaxf(m_, __shfl_xor(m_, 1));                               \
        m_ = fmaxf(m_, __shfl_xor(m_, 2));                               \
        m_ = fmaxf(m_, __shfl_xor(m_, 4));                               \
        m_ = fmaxf(m_, __shfl_xor(m_, 8));                               \
        m_ = fmaxf(m_, __shfl_xor(m_, 16));                              \
        int eb_ = (__float_as_int(m_) >> 23) & 0xff;                     \
        C2 += (float)(eb_ - 127);                                        \
        float sc2_ = __int_as_float((254 - eb_) << 23);                  \
        wcur *= sc2_;                                                    \
        if (lane < 32) wlds[lane] = wcur;                                \
    } while (0)

#define TLOAD(Q0, Q1, Q2, Q3, GR, SC) do {                               \
        const int s_ = (SC);                                             \
        if (s_ < L) {                                                    \
            const float*  p_  = cb + (size_t)s_ * s_stride;              \
            const float4* p4_ = (const float4*)p_;                       \
            Q0 = p4_[lane];       Q1 = p4_[64 + lane];                   \
            Q2 = p4_[128 + lane]; Q3 = p4_[192 + lane];                  \
            GR = p_[tg_lds[s_]];                                         \
        }                                                                \
    } while (0)

    // consumer phase: runtime j-loop (proven form), NO tg, NO per-step branch;
    // one renorm per phase after the loop (cadence = 8 steps, pow2-exact).
#define CONSUME(KK) do {                                                 \
        const int kb_ = (KK) & 1;                                        \
        const int jmax_ = min(NW, L - 1 - (KK) * NW);                    \
        for (int j = 0; j < jmax_; ++j) {                                \
            const float* eb = &ebuf[kb_][j][0];                          \
            float4 wa_ = *(const float4*)&wlds[fbase];                   \
            float4 wb_ = *(const float4*)&wlds[fbase + 4];               \
            float4 wc_ = *(const float4*)&wlds[fbase + 8];               \
            float4 wd_ = *(const float4*)&wlds[fbase + 12];              \
            float e_[16];                                                \
            _Pragma("unroll")                                            \
            for (int i = 0; i < 16; ++i)                                 \
                e_[i] = eb[((fbase + i) << 5) | t];                      \
            float s0_ = fmaf(e_[3], wa_.w, fmaf(e_[2], wa_.z,            \
                        fmaf(e_[1], wa_.y, e_[0] * wa_.x)));             \
            float s1_ = fmaf(e_[7], wb_.w, fmaf(e_[6], wb_.z,            \
                        fmaf(e_[5], wb_.y, e_[4] * wb_.x)));             \
            float s2_ = fmaf(e_[11], wc_.w, fmaf(e_[10], wc_.z,          \
                        fmaf(e_[9], wc_.y, e_[8] * wc_.x)));             \
            float s3_ = fmaf(e_[15], wd_.w, fmaf(e_[14], wd_.z,          \
                        fmaf(e_[13], wd_.y, e_[12] * wd_.x)));           \
            float s_ = (s0_ + s1_) + (s2_ + s3_);                        \
            s_ += __shfl_xor(s_, 32);                                    \
            wcur = s_;                                                   \
            if (lane < 32) wlds[lane] = s_;                              \
        }                                                                \
        RENORM;                                                          \
    } while (0)

    // One phase with buffer set (Q0..Q3,GQ): exp-write chunk KK (+ accumulate
    // its gold score), refill the SAME regs with chunk KK+2, raw barrier,
    // wave-0 consume. No register rotation anywhere (proven R12).
#define PHASE(Q0, Q1, Q2, Q3, GQ, KK) do {                               \
        const int k_ = (KK);                                             \
        const int scur_ = 1 + k_ * NW + wv;                              \
        if (scur_ < L) {                                                 \
            float4* ebw = (float4*)&ebuf[k_ & 1][wv][0];                 \
            float4 e0, e1, e2, e3;                                       \
            E4(e0, Q0); E4(e1, Q1); E4(e2, Q2); E4(e3, Q3);              \
            ebw[lane] = e0; ebw[64 + lane] = e1;                         \
            ebw[128 + lane] = e2; ebw[192 + lane] = e3;                  \
            tgacc += GQ;                                                 \
        }                                                                \
        TLOAD(Q0, Q1, Q2, Q3, GQ, scur_ + 2 * NW);                       \
        LGKM_BARRIER;                                                    \
        if (wv == 0) CONSUME(k_);                                        \
    } while (0)

    // ---- prologue prefetch: chunk 0 -> A, chunk 1 -> B ----
    float4 a0, a1, a2, a3, b0, b1, b2, b3;
    float ga = 0.0f, gb = 0.0f;
    TLOAD(a0, a1, a2, a3, ga, 1 + wv);
    TLOAD(b0, b1, b2, b3, gb, 1 + NW + wv);

    for (int k = 0; k < nch; k += 2) {
        PHASE(a0, a1, a2, a3, ga, k);
        if (k + 1 < nch)
            PHASE(b0, b1, b2, b3, gb, k + 1);
    }

    // ---- gold-path handoff: per-wave sums -> LDS -> wave 0 ----
    if (lane == 0) gfin[wv] = tgacc;
    __syncthreads();

    // ---- epilogue (consumer): logZ = ln(w[END_TAG]) + C2*ln2 ----
    if (wv == 0) {
        float tg = tg0;
#pragma unroll
        for (int w = 0; w < NW; ++w) tg += gfin[w];
        float wend = __shfl(wcur, END_TAG);
        float logZ = __logf(wend) + C2 * LN2;
        if (lane == 0)
            atomicAdd(out, (logZ - tg) * (1.0f / (float)B_));
    }
}

extern "C" void kernel_launch(void* const* d_in, const int* in_sizes, int n_in,
                              void* d_out, int out_size, void* d_ws, size_t ws_size,
                              hipStream_t stream) {
    const float* scores = (const float*)d_in[0];
    const int* targets  = (const int*)d_in[1];
    const void* mask    = d_in[2];
    const void* amask   = d_in[3];
    float* out = (float*)d_out;

    hipMemsetAsync(out, 0, sizeof(float), stream);
    crf_loss_kernel<<<dim3(A_ * B_), dim3(NW * 64), 0, stream>>>(
        scores, targets, mask, amask, out);
}